// Round 20
// baseline (1487.491 us; speedup 1.0000x reference)
//
#include <hip/hip_runtime.h>

#define SS 2048
#define HH 64

typedef _Float16 h2v __attribute__((ext_vector_type(2)));
typedef unsigned int uint;

__device__ __forceinline__ float fdot2f(uint w, uint x, float c) {
#if __has_builtin(__builtin_amdgcn_fdot2)
    return __builtin_amdgcn_fdot2(__builtin_bit_cast(h2v, w),
                                  __builtin_bit_cast(h2v, x), c, false);
#else
    h2v a = __builtin_bit_cast(h2v, w), bb = __builtin_bit_cast(h2v, x);
    return fmaf((float)a[0], (float)bb[0], fmaf((float)a[1], (float)bb[1], c));
#endif
}
__device__ __forceinline__ uint pack2(float a, float b) {
    h2v v = {(_Float16)a, (_Float16)b};
    return __builtin_bit_cast(uint, v);
}
__device__ __forceinline__ unsigned short f16bits(float a) {
    return __builtin_bit_cast(unsigned short, (_Float16)a);
}
__device__ __forceinline__ float fast_tanh(float x) {
    float ax = fabsf(x);
    float e = __expf(-2.0f * ax);
    float r = (1.0f - e) * __builtin_amdgcn_rcpf(1.0f + e);
    return copysignf(r, x);
}
__device__ __forceinline__ float fast_sigmoid(float x) {
    return __builtin_amdgcn_rcpf(1.0f + __expf(-x));
}

__global__ __launch_bounds__(128)
__attribute__((amdgpu_waves_per_eu(1, 1)))
void pgjanet_kernel(
    const float* __restrict__ x,     // [B,S,2]
    const float* __restrict__ h0,    // [1,B,H]
    const float* __restrict__ Wa,    // [65,64]
    const float* __restrict__ ba,
    const float* __restrict__ Wp1,
    const float* __restrict__ bp1,
    const float* __restrict__ Wp2,
    const float* __restrict__ bp2,
    const float* __restrict__ Wz,    // [128,64]
    const float* __restrict__ bz,
    const float* __restrict__ Wh,    // [128,64]
    const float* __restrict__ bh,
    const float* __restrict__ Wout,  // [64,2]
    const float* __restrict__ bout,
    float* __restrict__ out)         // [B,S,2]
{
    const int b   = blockIdx.x;
    const int tid = threadIdx.x;     // 0..127 (2 waves)
    const int j   = tid & 63;
    const int w   = tid >> 6;        // wave id: 0 -> zpre, 1 -> hpre + output

    __shared__ float2 xs2[SS];                              // 16 KB
    __shared__ __align__(16) unsigned short hpkW[2][64];    // per-wave h (f16)
    __shared__ __align__(16) unsigned short upkW[2][64];    // per-wave u (f16)
    __shared__ float zpreL[2][64];                          // parity-buffered
    __shared__ float hpreL[2][64];
    __shared__ float hbufL[32 * 65];                        // output stash
    __shared__ float WoutT[2 * 68];

    // ---- stage x[b] (coalesced, both waves) ----
    {
        const float2* xb = (const float2*)(x + (size_t)b * SS * 2);
        #pragma unroll
        for (int it = 0; it < SS / 128; ++it)
            xs2[tid + it * 128] = xb[tid + it * 128];
    }
    float bo_ = 0.f;
    if (w == 1) {
        WoutT[0 * 68 + j] = Wout[j * 2 + 0];
        WoutT[1 * 68 + j] = Wout[j * 2 + 1];
        bo_ = bout[j & 1];
    }

    // ---- per-lane scalars (both waves need gate params now) ----
    const float w0a  = Wa[j],  baR  = ba[j];
    const float w0p1 = Wp1[j], bp1R = bp1[j];
    const float w0p2 = Wp2[j], bp2R = bp2[j];
    const float bzR  = bz[j],  bhR  = bh[j];

    // ---- gate weights: 96 pairs, IDENTICAL in both waves ----
    uint wG[96];
    #pragma unroll
    for (int p = 0; p < 32; ++p) {
        wG[p]      = pack2(Wa [(1 + 2*p) * HH + j], Wa [(2 + 2*p) * HH + j]);
        wG[32 + p] = pack2(Wp1[(1 + 2*p) * HH + j], Wp1[(2 + 2*p) * HH + j]);
        wG[64 + p] = pack2(Wp2[(1 + 2*p) * HH + j], Wp2[(2 + 2*p) * HH + j]);
    }
    // ---- side weights: wave-dependent sources (shared register slots) ----
    //   W0: h-side = Wz[64:], u-side = Wz[:64]   (-> zpre)
    //   W1: h-side = Wh[64:], u-side = Wh[:64]   (-> hpre)
    const float* hsW = (w == 0) ? (Wz + 64 * HH) : (Wh + 64 * HH);
    const float* usW = (w == 0) ? Wz : Wh;
    uint wHs[32], wUs[32];
    #pragma unroll
    for (int p = 0; p < 32; ++p) {
        wHs[p] = pack2(hsW[(2 * p) * HH + j], hsW[(2 * p + 1) * HH + j]);
        wUs[p] = pack2(usW[(2 * p) * HH + j], usW[(2 * p + 1) * HH + j]);
    }
    // pin (opaque -> cannot be sunk/rematerialized into the loop)
    #pragma unroll
    for (int k = 0; k < 96; ++k) asm volatile("" : "+v"(wG[k]));
    #pragma unroll
    for (int k = 0; k < 32; ++k) asm volatile("" : "+a"(wHs[k]), "+a"(wUs[k]));

    // ---- initial hidden state: f32 reg + per-wave f16 LDS copy ----
    float hreg = h0[b * HH + j];
    hpkW[w][j] = f16bits(hreg);

    // ---- prefetched scalar inputs for t=0 (both waves) ----
    float amp, ca, sa;
    {
        const float2 xt = xs2[0];
        const float d = xt.x * xt.x + xt.y * xt.y;
        const float inv = (d > 0.f) ? __builtin_amdgcn_rsqf(d) : 0.f;
        amp = d * inv;
        ca  = (d > 0.f) ? xt.x * inv : 1.0f;
        sa  = xt.y * inv;
    }

    __syncthreads();   // xs2/WoutT staged, initial hpkW visible

    for (int t = 0; t < SS; ++t) {
        const int par = t & 1;

        // ---- own-wave h broadcast (scalar assigns, const idx) ----
        uint hp[32];
        {
            const uint4* hp4 = (const uint4*)hpkW[w];
            #pragma unroll
            for (int g = 0; g < 8; ++g) {
                uint4 v = hp4[g];
                hp[4*g+0] = v.x; hp[4*g+1] = v.y;
                hp[4*g+2] = v.z; hp[4*g+3] = v.w;
            }
        }

        // ---- gates (96 fdot2, redundant on BOTH waves) ----
        float aA0 = 0.f, aA1 = 0.f, aP10 = 0.f, aP11 = 0.f, aP20 = 0.f, aP21 = 0.f;
        #pragma unroll
        for (int g = 0; g < 8; ++g) {
            aA0  = fdot2f(wG[4*g+0],    hp[4*g+0], aA0);
            aA1  = fdot2f(wG[4*g+1],    hp[4*g+1], aA1);
            aA0  = fdot2f(wG[4*g+2],    hp[4*g+2], aA0);
            aA1  = fdot2f(wG[4*g+3],    hp[4*g+3], aA1);
            aP10 = fdot2f(wG[32+4*g+0], hp[4*g+0], aP10);
            aP11 = fdot2f(wG[32+4*g+1], hp[4*g+1], aP11);
            aP10 = fdot2f(wG[32+4*g+2], hp[4*g+2], aP10);
            aP11 = fdot2f(wG[32+4*g+3], hp[4*g+3], aP11);
            aP20 = fdot2f(wG[64+4*g+0], hp[4*g+0], aP20);
            aP21 = fdot2f(wG[64+4*g+1], hp[4*g+1], aP21);
            aP20 = fdot2f(wG[64+4*g+2], hp[4*g+2], aP20);
            aP21 = fdot2f(wG[64+4*g+3], hp[4*g+3], aP21);
        }
        const float a_  = fast_tanh(aA0 + aA1 + fmaf(amp, w0a,  baR));
        const float p1_ = fast_tanh(aP10 + aP11 + fmaf(ca, w0p1, bp1R));
        const float p2_ = fast_tanh(aP20 + aP21 + fmaf(sa, w0p2, bp2R));
        const float u = a_ * p1_ * p2_ * (1.f - a_) * (1.f - p1_) * (1.f - p2_);

        // ---- own-wave u round-trip (same-wave DS: in-order, no barrier) ----
        upkW[w][j] = f16bits(u);
        uint up[32];
        {
            const uint4* up4 = (const uint4*)upkW[w];
            #pragma unroll
            for (int g = 0; g < 8; ++g) {
                uint4 v = up4[g];
                up[4*g+0] = v.x; up[4*g+1] = v.y;
                up[4*g+2] = v.z; up[4*g+3] = v.w;
            }
        }

        // ---- h-side matvec (32 fdot2) — covers the u-read latency ----
        float hs0 = 0.f, hs1 = 0.f, hs2 = 0.f, hs3 = 0.f;
        #pragma unroll
        for (int p = 0; p < 32; p += 4) {
            hs0 = fdot2f(wHs[p + 0], hp[p + 0], hs0);
            hs1 = fdot2f(wHs[p + 1], hp[p + 1], hs1);
            hs2 = fdot2f(wHs[p + 2], hp[p + 2], hs2);
            hs3 = fdot2f(wHs[p + 3], hp[p + 3], hs3);
        }
        const float hside = (hs0 + hs1) + (hs2 + hs3);

        // ---- next step's scalar inputs (also in the shadow) ----
        {
            const float2 xn = xs2[(t + 1) & (SS - 1)];
            const float dn = xn.x * xn.x + xn.y * xn.y;
            const float invn = (dn > 0.f) ? __builtin_amdgcn_rsqf(dn) : 0.f;
            amp = dn * invn;
            ca  = (dn > 0.f) ? xn.x * invn : 1.0f;
            sa  = xn.y * invn;
        }

        // ---- u-side matvec (32 fdot2, full 64-dot) ----
        float us0 = 0.f, us1 = 0.f, us2 = 0.f, us3 = 0.f;
        #pragma unroll
        for (int p = 0; p < 32; p += 4) {
            us0 = fdot2f(wUs[p + 0], up[p + 0], us0);
            us1 = fdot2f(wUs[p + 1], up[p + 1], us1);
            us2 = fdot2f(wUs[p + 2], up[p + 2], us2);
            us3 = fdot2f(wUs[p + 3], up[p + 3], us3);
        }
        const float mypre = (us0 + us1) + (us2 + us3) + hside;

        // ---- exchange one float each way (parity-buffered) ----
        if (w == 0) zpreL[par][j] = mypre;
        else        hpreL[par][j] = mypre;
        __syncthreads();   // THE single barrier per step

        const float zpre = (w == 0) ? mypre : zpreL[par][j];
        const float hpre = (w == 0) ? hpreL[par][j] : mypre;

        // ---- combine (both waves redundantly; h stays f32 in regs) ----
        const float z  = fast_sigmoid(zpre + bzR);
        const float hc = fast_tanh(hpre + bhR);
        hreg = fmaf(z, hreg - hc, hc);
        hpkW[w][j] = f16bits(hreg);    // own copy for next step (in-order)

        // ---- output stash + flush (wave 1 only, same-wave in-order) ----
        if (w == 1) {
            hbufL[(t & 31) * 65 + j] = hreg;
            if ((t & 31) == 31) {
                const int r = j >> 1, o2 = j & 1;
                float acc = 0.f;
                #pragma unroll
                for (int k = 0; k < 64; ++k)
                    acc += hbufL[r * 65 + k] * WoutT[o2 * 68 + k];
                out[((size_t)b * SS + (t - 31 + r)) * 2 + o2] = acc + bo_;
            }
        }
        // hazards: zpreL/hpreL parity-buffered — read(t) completes before
        // bar(t+1) (waitcnt at barrier), same-slot write is at t+2 after
        // bar(t+1): safe. hpkW/upkW/hbufL are own-wave in-order.
    }
}

extern "C" void kernel_launch(void* const* d_in, const int* in_sizes, int n_in,
                              void* d_out, int out_size, void* d_ws, size_t ws_size,
                              hipStream_t stream) {
    const float* x    = (const float*)d_in[0];
    const float* h0   = (const float*)d_in[1];
    const float* Wa   = (const float*)d_in[2];
    const float* ba   = (const float*)d_in[3];
    const float* Wp1  = (const float*)d_in[4];
    const float* bp1  = (const float*)d_in[5];
    const float* Wp2  = (const float*)d_in[6];
    const float* bp2  = (const float*)d_in[7];
    const float* Wz   = (const float*)d_in[8];
    const float* bz   = (const float*)d_in[9];
    const float* Wh   = (const float*)d_in[10];
    const float* bh   = (const float*)d_in[11];
    const float* Wout = (const float*)d_in[12];
    const float* bout = (const float*)d_in[13];
    float* out = (float*)d_out;

    pgjanet_kernel<<<256, 128, 0, stream>>>(x, h0, Wa, ba, Wp1, bp1, Wp2, bp2,
                                            Wz, bz, Wh, bh, Wout, bout, out);
}

// Round 21
// 1434.579 us; speedup vs baseline: 1.0369x; 1.0369x over previous
//
#include <hip/hip_runtime.h>

#define SS 2048
#define HH 64

typedef _Float16 h2v __attribute__((ext_vector_type(2)));
typedef unsigned int uint;

__device__ __forceinline__ float fdot2f(uint w, uint x, float c) {
#if __has_builtin(__builtin_amdgcn_fdot2)
    return __builtin_amdgcn_fdot2(__builtin_bit_cast(h2v, w),
                                  __builtin_bit_cast(h2v, x), c, false);
#else
    h2v a = __builtin_bit_cast(h2v, w), bb = __builtin_bit_cast(h2v, x);
    return fmaf((float)a[0], (float)bb[0], fmaf((float)a[1], (float)bb[1], c));
#endif
}
__device__ __forceinline__ uint pack2(float a, float b) {
    h2v v = {(_Float16)a, (_Float16)b};
    return __builtin_bit_cast(uint, v);
}
__device__ __forceinline__ unsigned short f16bits(float a) {
    return __builtin_bit_cast(unsigned short, (_Float16)a);
}
__device__ __forceinline__ float fast_tanh(float x) {
    float ax = fabsf(x);
    float e = __expf(-2.0f * ax);
    float r = (1.0f - e) * __builtin_amdgcn_rcpf(1.0f + e);
    return copysignf(r, x);
}
__device__ __forceinline__ float fast_sigmoid(float x) {
    return __builtin_amdgcn_rcpf(1.0f + __expf(-x));
}

__global__ __launch_bounds__(128)
__attribute__((amdgpu_waves_per_eu(1, 1)))
void pgjanet_kernel(
    const float* __restrict__ x,     // [B,S,2]
    const float* __restrict__ h0,    // [1,B,H]
    const float* __restrict__ Wa,    // [65,64]
    const float* __restrict__ ba,
    const float* __restrict__ Wp1,
    const float* __restrict__ bp1,
    const float* __restrict__ Wp2,
    const float* __restrict__ bp2,
    const float* __restrict__ Wz,    // [128,64]
    const float* __restrict__ bz,
    const float* __restrict__ Wh,    // [128,64]
    const float* __restrict__ bh,
    const float* __restrict__ Wout,  // [64,2]
    const float* __restrict__ bout,
    float* __restrict__ out)         // [B,S,2]
{
    const int b   = blockIdx.x;
    const int tid = threadIdx.x;     // 0..127 (2 waves)
    const int j   = tid & 63;
    const int w   = tid >> 6;        // wave id: 0 = gates/u, 1 = zh/hh+output

    __shared__ float2 xs2[SS];                              // 16 KB
    __shared__ __align__(16) unsigned short hpkW[2][64];    // per-wave h (f16)
    __shared__ __align__(16) unsigned short upk[64];        // u (f16), W0-owned
    __shared__ __align__(8) float2 zhhhL[2][64];            // W1 ph1 out, parity
    __shared__ __align__(8) float2 szshL[2][2][64];         // [wave][parity]
    __shared__ float hbufL[32 * 65];                        // output stash
    __shared__ float WoutT[2 * 68];

    // ---- stage x[b] (coalesced, both waves) ----
    {
        const float2* xb = (const float2*)(x + (size_t)b * SS * 2);
        #pragma unroll
        for (int it = 0; it < SS / 128; ++it)
            xs2[tid + it * 128] = xb[tid + it * 128];
    }
    float bo_ = 0.f;
    if (w == 1) {
        WoutT[0 * 68 + j] = Wout[j * 2 + 0];
        WoutT[1 * 68 + j] = Wout[j * 2 + 1];
        bo_ = bout[j & 1];
    }

    // ---- per-lane scalars ----
    float w0a = 0.f, baR = 0.f, w0p1 = 0.f, bp1R = 0.f, w0p2 = 0.f, bp2R = 0.f;
    if (w == 0) {
        w0a = Wa[j];  baR  = ba[j];
        w0p1 = Wp1[j]; bp1R = bp1[j];
        w0p2 = Wp2[j]; bp2R = bp2[j];
    }
    const float bzR = bz[j], bhR = bh[j];

    // ---- phase-1 weights: SHARED register slots, wave-specific sources ----
    const float* src0;
    const float* src1;
    const float* src2;
    if (w == 0) { src0 = Wa + HH;      src1 = Wp1 + HH;     src2 = Wp2 + HH; }
    else        { src0 = Wz + 64 * HH; src1 = Wh + 64 * HH; src2 = Wz + 64 * HH; }

    uint wph1[96];
    #pragma unroll
    for (int p = 0; p < 32; ++p) {
        wph1[p]      = pack2(src0[(2 * p) * HH + j], src0[(2 * p + 1) * HH + j]);
        wph1[32 + p] = pack2(src1[(2 * p) * HH + j], src1[(2 * p + 1) * HH + j]);
        wph1[64 + p] = pack2(src2[(2 * p) * HH + j], src2[(2 * p + 1) * HH + j]);
    }
    // ---- phase-2 half weights: wave w covers k in [32w, 32w+32) ----
    uint wZ2[16], wH2[16];
    {
        const int kb = 32 * w;
        #pragma unroll
        for (int p = 0; p < 16; ++p) {
            wZ2[p] = pack2(Wz[(kb + 2 * p) * HH + j], Wz[(kb + 2 * p + 1) * HH + j]);
            wH2[p] = pack2(Wh[(kb + 2 * p) * HH + j], Wh[(kb + 2 * p + 1) * HH + j]);
        }
    }
    // pin (opaque -> cannot be sunk/rematerialized into the loop)
    #pragma unroll
    for (int k = 0; k < 96; ++k) asm volatile("" : "+v"(wph1[k]));
    #pragma unroll
    for (int k = 0; k < 16; ++k) asm volatile("" : "+a"(wZ2[k]), "+a"(wH2[k]));

    // ---- initial hidden state: f32 reg + per-wave f16 LDS copy ----
    float hreg = h0[b * HH + j];
    hpkW[w][j] = f16bits(hreg);

    // ---- prefetched scalar inputs for t=0 (W0 only; same-wave xs2 reads) ----
    float amp = 0.f, ca = 0.f, sa = 0.f;
    if (w == 0) {
        const float2 xt = xs2[0];
        const float d = xt.x * xt.x + xt.y * xt.y;
        const float inv = (d > 0.f) ? __builtin_amdgcn_rsqf(d) : 0.f;
        amp = d * inv;
        ca  = (d > 0.f) ? xt.x * inv : 1.0f;
        sa  = xt.y * inv;
    }

    __syncthreads();   // xs2/WoutT staged, initial hpkW visible

    for (int t = 0; t < SS; ++t) {
        const int par = t & 1;

        // ---- own-wave h broadcast (scalar assigns, const idx) ----
        uint hp[32];
        {
            const uint4* hp4 = (const uint4*)hpkW[w];
            #pragma unroll
            for (int g = 0; g < 8; ++g) {
                uint4 v = hp4[g];
                hp[4*g+0] = v.x; hp[4*g+1] = v.y;
                hp[4*g+2] = v.z; hp[4*g+3] = v.w;
            }
        }

        // ---- PHASE 1 ----
        float zh_r = 0.f, hh_r = 0.f;   // W1 keeps these in regs
        if (w == 0) {
            float aA0 = 0.f, aA1 = 0.f, aP10 = 0.f, aP11 = 0.f, aP20 = 0.f, aP21 = 0.f;
            #pragma unroll
            for (int g = 0; g < 8; ++g) {
                aA0  = fdot2f(wph1[4*g+0],      hp[4*g+0], aA0);
                aA1  = fdot2f(wph1[4*g+1],      hp[4*g+1], aA1);
                aA0  = fdot2f(wph1[4*g+2],      hp[4*g+2], aA0);
                aA1  = fdot2f(wph1[4*g+3],      hp[4*g+3], aA1);
                aP10 = fdot2f(wph1[32+4*g+0],   hp[4*g+0], aP10);
                aP11 = fdot2f(wph1[32+4*g+1],   hp[4*g+1], aP11);
                aP10 = fdot2f(wph1[32+4*g+2],   hp[4*g+2], aP10);
                aP11 = fdot2f(wph1[32+4*g+3],   hp[4*g+3], aP11);
                aP20 = fdot2f(wph1[64+4*g+0],   hp[4*g+0], aP20);
                aP21 = fdot2f(wph1[64+4*g+1],   hp[4*g+1], aP21);
                aP20 = fdot2f(wph1[64+4*g+2],   hp[4*g+2], aP20);
                aP21 = fdot2f(wph1[64+4*g+3],   hp[4*g+3], aP21);
            }
            const float a_  = fast_tanh(aA0 + aA1 + fmaf(amp, w0a,  baR));
            const float p1_ = fast_tanh(aP10 + aP11 + fmaf(ca, w0p1, bp1R));
            const float p2_ = fast_tanh(aP20 + aP21 + fmaf(sa, w0p2, bp2R));
            const float u = a_ * p1_ * p2_ * (1.f - a_) * (1.f - p1_) * (1.f - p2_);
            upk[j] = f16bits(u);
        } else {
            float z0 = 0.f, z1 = 0.f, h0r = 0.f, h1r = 0.f;
            #pragma unroll
            for (int g = 0; g < 8; ++g) {
                z0  = fdot2f(wph1[4*g+0],    hp[4*g+0], z0);
                z1  = fdot2f(wph1[4*g+1],    hp[4*g+1], z1);
                z0  = fdot2f(wph1[4*g+2],    hp[4*g+2], z0);
                z1  = fdot2f(wph1[4*g+3],    hp[4*g+3], z1);
                h0r = fdot2f(wph1[32+4*g+0], hp[4*g+0], h0r);
                h1r = fdot2f(wph1[32+4*g+1], hp[4*g+1], h1r);
                h0r = fdot2f(wph1[32+4*g+2], hp[4*g+2], h0r);
                h1r = fdot2f(wph1[32+4*g+3], hp[4*g+3], h1r);
            }
            zh_r = z0 + z1;
            hh_r = h0r + h1r;
            zhhhL[par][j] = make_float2(zh_r, hh_r);   // for W0's combine
        }
        __syncthreads();   // barrier A: upk (and zhhhL) visible

        // ---- W0: prefetch (zh,hh) now; latency hides under phase 2 ----
        float2 zhhh_w0 = make_float2(0.f, 0.f);
        if (w == 0) zhhh_w0 = zhhhL[par][j];

        // ---- PHASE 2: both waves, own k-half of u@Wz / u@Wh ----
        float sz, sh;
        {
            uint up[16];
            {
                const uint4* up4 = (const uint4*)(upk + 32 * w);
                #pragma unroll
                for (int g = 0; g < 4; ++g) {
                    uint4 v = up4[g];
                    up[4*g+0] = v.x; up[4*g+1] = v.y;
                    up[4*g+2] = v.z; up[4*g+3] = v.w;
                }
            }
            // W0: compute next step's scalar inputs in the u-read shadow
            if (w == 0) {
                const float2 xn = xs2[(t + 1) & (SS - 1)];
                const float dn = xn.x * xn.x + xn.y * xn.y;
                const float invn = (dn > 0.f) ? __builtin_amdgcn_rsqf(dn) : 0.f;
                amp = dn * invn;
                ca  = (dn > 0.f) ? xn.x * invn : 1.0f;
                sa  = xn.y * invn;
            }
            float sz0 = 0.f, sz1 = 0.f, sh0 = 0.f, sh1 = 0.f;
            #pragma unroll
            for (int p = 0; p < 16; p += 2) {
                sz0 = fdot2f(wZ2[p + 0], up[p + 0], sz0);
                sz1 = fdot2f(wZ2[p + 1], up[p + 1], sz1);
                sh0 = fdot2f(wH2[p + 0], up[p + 0], sh0);
                sh1 = fdot2f(wH2[p + 1], up[p + 1], sh1);
            }
            sz = sz0 + sz1;
            sh = sh0 + sh1;
            szshL[w][par][j] = make_float2(sz, sh);
        }
        __syncthreads();   // barrier B: partials visible

        // ---- COMBINE (both waves redundantly; h stays f32 in regs) ----
        {
            float zh_t, hh_t;
            float2 o;
            if (w == 0) {
                zh_t = zhhh_w0.x; hh_t = zhhh_w0.y;
                o = szshL[1][par][j];
            } else {
                zh_t = zh_r; hh_t = hh_r;
                o = szshL[0][par][j];
            }
            const float z  = fast_sigmoid(sz + o.x + zh_t + bzR);
            const float hc = fast_tanh(sh + o.y + hh_t + bhR);
            hreg = fmaf(z, hreg - hc, hc);
            hpkW[w][j] = f16bits(hreg);    // own copy for next step (in-order)
        }

        // ---- output stash + flush (wave 1 only, same-wave in-order) ----
        if (w == 1) {
            hbufL[(t & 31) * 65 + j] = hreg;
            if ((t & 31) == 31) {
                const int r = j >> 1, o2 = j & 1;
                float acc = 0.f;
                #pragma unroll
                for (int k = 0; k < 64; ++k)
                    acc += hbufL[r * 65 + k] * WoutT[o2 * 68 + k];
                out[((size_t)b * SS + (t - 31 + r)) * 2 + o2] = acc + bo_;
            }
        }
        // hazards: upk W1-read(t) < barB(t) < W0-write(t+1); zhhhL read(t,
        // post-barA) vs write(t+2, pre-barA) separated by >=2 barriers;
        // szshL parity-buffered; hpkW/hbufL same-wave in-order.
    }
}

extern "C" void kernel_launch(void* const* d_in, const int* in_sizes, int n_in,
                              void* d_out, int out_size, void* d_ws, size_t ws_size,
                              hipStream_t stream) {
    const float* x    = (const float*)d_in[0];
    const float* h0   = (const float*)d_in[1];
    const float* Wa   = (const float*)d_in[2];
    const float* ba   = (const float*)d_in[3];
    const float* Wp1  = (const float*)d_in[4];
    const float* bp1  = (const float*)d_in[5];
    const float* Wp2  = (const float*)d_in[6];
    const float* bp2  = (const float*)d_in[7];
    const float* Wz   = (const float*)d_in[8];
    const float* bz   = (const float*)d_in[9];
    const float* Wh   = (const float*)d_in[10];
    const float* bh   = (const float*)d_in[11];
    const float* Wout = (const float*)d_in[12];
    const float* bout = (const float*)d_in[13];
    float* out = (float*)d_out;

    pgjanet_kernel<<<256, 128, 0, stream>>>(x, h0, Wa, ba, Wp1, bp1, Wp2, bp2,
                                            Wz, bz, Wh, bh, Wout, bout, out);
}